// Round 2
// baseline (1444.821 us; speedup 1.0000x reference)
//
#include <hip/hip_runtime.h>
#include <cstddef>

#define NF 64
#define EF 16
#define NH 128
#define EH 128
#define MA 256

static inline int ceil_div(int a, int b) { return (a + b - 1) / b; }

// ---------------- generic fp32 GEMM ----------------
// C[M,Nc] = act( A[M,K] @ Bw[K,Nc] + addR[addIdx? addIdx[r] : r] + bias )
// BM=BN=64, BK=16, 256 threads, 4x4 per thread. M%64==0, Nc%64==0, K%16==0.
__global__ __launch_bounds__(256) void gemm_kernel(
    const float* __restrict__ A, const float* __restrict__ Bw,
    float* __restrict__ C,
    const float* __restrict__ addR, const int* __restrict__ addIdx,
    const float* __restrict__ bias,
    int M, int K, int Nc, int doRelu)
{
    __shared__ float As[16][64];   // [k][m]
    __shared__ float Bs[16][64];   // [k][n]
    const int tid = threadIdx.x;
    const int tx = tid & 15, ty = tid >> 4;
    const int m0 = blockIdx.y << 6;
    const int n0 = blockIdx.x << 6;
    const int lr = tid >> 2;           // A tile row 0..63
    const int lc = (tid & 3) << 2;     // A tile col (float4) 0,4,8,12
    const int bkr = tid >> 4;          // B tile k-row 0..15
    const int bc = (tid & 15) << 2;    // B tile col 0..60

    float acc[4][4];
#pragma unroll
    for (int i = 0; i < 4; ++i)
#pragma unroll
        for (int j = 0; j < 4; ++j) acc[i][j] = 0.0f;

    for (int k0 = 0; k0 < K; k0 += 16) {
        float4 a4 = *(const float4*)(A + (size_t)(m0 + lr) * K + (k0 + lc));
        float4 b4 = *(const float4*)(Bw + (size_t)(k0 + bkr) * Nc + (n0 + bc));
        __syncthreads();
        As[lc + 0][lr] = a4.x;
        As[lc + 1][lr] = a4.y;
        As[lc + 2][lr] = a4.z;
        As[lc + 3][lr] = a4.w;
        *(float4*)&Bs[bkr][bc] = b4;
        __syncthreads();
#pragma unroll
        for (int kk = 0; kk < 16; ++kk) {
            float a0 = As[kk][ty * 4 + 0];
            float a1 = As[kk][ty * 4 + 1];
            float a2 = As[kk][ty * 4 + 2];
            float a3 = As[kk][ty * 4 + 3];
            float b0 = Bs[kk][tx * 4 + 0];
            float b1 = Bs[kk][tx * 4 + 1];
            float b2 = Bs[kk][tx * 4 + 2];
            float b3 = Bs[kk][tx * 4 + 3];
            acc[0][0] += a0 * b0; acc[0][1] += a0 * b1; acc[0][2] += a0 * b2; acc[0][3] += a0 * b3;
            acc[1][0] += a1 * b0; acc[1][1] += a1 * b1; acc[1][2] += a1 * b2; acc[1][3] += a1 * b3;
            acc[2][0] += a2 * b0; acc[2][1] += a2 * b1; acc[2][2] += a2 * b2; acc[2][3] += a2 * b3;
            acc[3][0] += a3 * b0; acc[3][1] += a3 * b1; acc[3][2] += a3 * b2; acc[3][3] += a3 * b3;
        }
    }

    const int c = n0 + tx * 4;
    float4 bv = make_float4(0.f, 0.f, 0.f, 0.f);
    if (bias) bv = *(const float4*)(bias + c);
#pragma unroll
    for (int i = 0; i < 4; ++i) {
        int r = m0 + ty * 4 + i;
        float4 v = make_float4(acc[i][0], acc[i][1], acc[i][2], acc[i][3]);
        if (addR) {
            int ar = addIdx ? addIdx[r] : r;
            float4 ad = *(const float4*)(addR + (size_t)ar * Nc + c);
            v.x += ad.x; v.y += ad.y; v.z += ad.z; v.w += ad.w;
        }
        v.x += bv.x; v.y += bv.y; v.z += bv.z; v.w += bv.w;
        if (doRelu) {
            v.x = fmaxf(v.x, 0.f); v.y = fmaxf(v.y, 0.f);
            v.z = fmaxf(v.z, 0.f); v.w = fmaxf(v.w, 0.f);
        }
        *(float4*)(C + (size_t)r * Nc + c) = v;
    }
}

// ---------------- CSR build ----------------
__global__ __launch_bounds__(256) void hist_kernel(const int* __restrict__ dst, int* __restrict__ deg, int E) {
    int e = blockIdx.x * 256 + threadIdx.x;
    if (e < E) atomicAdd(&deg[dst[e]], 1);
}

__global__ __launch_bounds__(256) void scan_block_kernel(const int* __restrict__ deg, int* __restrict__ rp,
                                                         int* __restrict__ bsum) {
    __shared__ int buf[256];
    int tid = threadIdx.x;
    int i = blockIdx.x * 256 + tid;
    int v = deg[i];
    buf[tid] = v;
    __syncthreads();
    for (int off = 1; off < 256; off <<= 1) {
        int t = (tid >= off) ? buf[tid - off] : 0;
        __syncthreads();
        buf[tid] += t;
        __syncthreads();
    }
    rp[i] = buf[tid] - v;
    if (tid == 255) bsum[blockIdx.x] = buf[255];
}

__global__ __launch_bounds__(256) void scan_top_kernel(const int* __restrict__ bsum, int* __restrict__ boff,
                                                       int* __restrict__ rp, int N) {
    __shared__ int buf[256];
    int tid = threadIdx.x;
    int v = bsum[tid];
    buf[tid] = v;
    __syncthreads();
    for (int off = 1; off < 256; off <<= 1) {
        int t = (tid >= off) ? buf[tid - off] : 0;
        __syncthreads();
        buf[tid] += t;
        __syncthreads();
    }
    boff[tid] = buf[tid] - v;
    if (tid == 255) rp[N] = buf[255];
}

__global__ __launch_bounds__(256) void scan_add_kernel(int* __restrict__ rp, int* __restrict__ cursor,
                                                       const int* __restrict__ boff) {
    int tid = threadIdx.x;
    int i = blockIdx.x * 256 + tid;
    int v = rp[i] + boff[blockIdx.x];
    rp[i] = v;
    cursor[i] = v;
}

__global__ __launch_bounds__(256) void scatter_kernel(const int* __restrict__ dst, int* __restrict__ cursor,
                                                      int* __restrict__ eid, int E) {
    int e = blockIdx.x * 256 + threadIdx.x;
    if (e < E) {
        int p = atomicAdd(&cursor[dst[e]], 1);
        eid[p] = e;
    }
}

// ---------------- elementwise relu copy ----------------
__global__ __launch_bounds__(256) void relu_copy_kernel(const float* __restrict__ in, float* __restrict__ out, int n4) {
    int i = blockIdx.x * 256 + threadIdx.x;
    if (i < n4) {
        float4 v = ((const float4*)in)[i];
        v.x = fmaxf(v.x, 0.f); v.y = fmaxf(v.y, 0.f);
        v.z = fmaxf(v.z, 0.f); v.w = fmaxf(v.w, 0.f);
        ((float4*)out)[i] = v;
    }
}

// ---------------- edge aggregation via CSR (gather, no atomics) ----------------
// agg[n][c] = sum over incoming edges e of relu(nodeT[src[e]][c] + W2e[e][c])
__global__ __launch_bounds__(128) void agg_kernel(const float* __restrict__ nodeT, const float* __restrict__ W2e,
                                                  const int* __restrict__ rp, const int* __restrict__ eid,
                                                  const int* __restrict__ src, float* __restrict__ agg) {
    int n = blockIdx.x * 4 + threadIdx.y;
    int c = threadIdx.x << 2;  // 32 threads x float4 = 128 cols
    int p0 = rp[n], p1 = rp[n + 1];
    float4 s = make_float4(0.f, 0.f, 0.f, 0.f);
    for (int p = p0; p < p1; ++p) {
        int e = eid[p];
        int sn = src[e];
        float4 t = *(const float4*)(nodeT + (size_t)sn * EH + c);
        float4 w = *(const float4*)(W2e + (size_t)e * EH + c);
        s.x += fmaxf(t.x + w.x, 0.f);
        s.y += fmaxf(t.y + w.y, 0.f);
        s.z += fmaxf(t.z + w.z, 0.f);
        s.w += fmaxf(t.w + w.w, 0.f);
    }
    *(float4*)(agg + (size_t)n * EH + c) = s;
}

// ---------------- final layer: z = x3 @ M4w + b; out = (z>=0) as int32 ----------------
__global__ __launch_bounds__(256) void final_kernel(const float* __restrict__ x3, const float* __restrict__ w,
                                                    const float* __restrict__ b, int* __restrict__ out, int Nn) {
    int g = blockIdx.x * 256 + threadIdx.x;
    int n = g >> 6;
    int lane = threadIdx.x & 63;
    if (n < Nn) {
        float v = x3[(size_t)n * 64 + lane] * w[lane];
#pragma unroll
        for (int off = 32; off > 0; off >>= 1) v += __shfl_xor(v, off, 64);
        if (lane == 0) out[n] = (v + b[0]) >= 0.f ? 1 : 0;
    }
}

extern "C" void kernel_launch(void* const* d_in, const int* in_sizes, int n_in,
                              void* d_out, int out_size, void* d_ws, size_t ws_size,
                              hipStream_t stream)
{
    const float* mol_a = (const float*)d_in[0];
    const float* nf    = (const float*)d_in[1];
    const float* ef    = (const float*)d_in[2];
    const int*   edges = (const int*)d_in[5];
    const int*   batch = (const int*)d_in[6];
    const float* W1  = (const float*)d_in[7];
    const float* W2  = (const float*)d_in[8];
    const float* W3  = (const float*)d_in[9];
    const float* U1  = (const float*)d_in[10];
    const float* U2  = (const float*)d_in[11];
    const float* M1w = (const float*)d_in[12];
    const float* M1b = (const float*)d_in[13];
    const float* M2w = (const float*)d_in[14];
    const float* M2b = (const float*)d_in[15];
    const float* M3w = (const float*)d_in[16];
    const float* M3b = (const float*)d_in[17];
    const float* M4w = (const float*)d_in[18];
    const float* M4b = (const float*)d_in[19];

    const int N = in_sizes[3] / NH;   // 65536
    const int E = in_sizes[4] / EH;   // 262144
    const int B = in_sizes[0] / MA;   // 2048
    const int* srcp = edges;
    const int* dstp = edges + E;

    char* ws = (char*)d_ws;
    size_t off = 0;
    auto alloc = [&](size_t bytes) -> char* {
        char* p = ws + off;
        off = (off + bytes + 255) & ~(size_t)255;
        return p;
    };
    int* deg     = (int*)alloc((size_t)N * 4);
    int* rp      = (int*)alloc(((size_t)N + 1) * 4);
    int* cursor  = (int*)alloc((size_t)N * 4);
    int* bsum    = (int*)alloc(256 * 4);
    int* boff    = (int*)alloc(256 * 4);
    int* eid     = (int*)alloc((size_t)E * 4);
    float* nodePre = (float*)alloc((size_t)N * EH * 4);
    float* U1x     = (float*)alloc((size_t)N * NH * 4);
    float* node_h  = (float*)alloc((size_t)N * NH * 4);
    float* nodeT   = (float*)alloc((size_t)N * EH * 4);
    float* aggp    = (float*)alloc((size_t)N * EH * 4);
    float* molPart = (float*)alloc((size_t)B * 256 * 4);
    float* W2e     = (float*)alloc((size_t)E * EH * 4);
    // MLP phase reuses dead buffers:
    float* x1 = (float*)W2e;   // [N,256] (67MB <= 134MB)
    float* x2 = nodeT;         // [N,128]
    float* x3 = aggp;          // [N,64]

    // ---- CSR build (dst is loop-invariant) ----
    hipMemsetAsync(deg, 0, (size_t)N * 4, stream);
    hist_kernel<<<ceil_div(E, 256), 256, 0, stream>>>(dstp, deg, E);
    scan_block_kernel<<<N / 256, 256, 0, stream>>>(deg, rp, bsum);
    scan_top_kernel<<<1, 256, 0, stream>>>(bsum, boff, rp, N);
    scan_add_kernel<<<N / 256, 256, 0, stream>>>(rp, cursor, boff);
    scatter_kernel<<<ceil_div(E, 256), 256, 0, stream>>>(dstp, cursor, eid, E);

    // ---- loop-invariant precompute ----
    gemm_kernel<<<dim3(EH / 64, N / 64), 256, 0, stream>>>(nf, W1, nodePre, nullptr, nullptr, nullptr, N, NF, EH, 0);
    gemm_kernel<<<dim3(EH / 64, E / 64), 256, 0, stream>>>(ef, W2, W2e, nullptr, nullptr, nullptr, E, EF, EH, 0);
    gemm_kernel<<<dim3(NH / 64, N / 64), 256, 0, stream>>>(nf, U1, U1x, nullptr, nullptr, nullptr, N, NF, NH, 0);

    // ---- step 1: edge_h0 == 0 -> agg == 0 -> node_h = relu(U1x) ----
    relu_copy_kernel<<<(N * NH / 4) / 256, 256, 0, stream>>>(U1x, node_h, N * NH / 4);

    // ---- steps 2..8 ----
    for (int s = 0; s < 7; ++s) {
        // nodeT = nodePre + node_h @ W3
        gemm_kernel<<<dim3(EH / 64, N / 64), 256, 0, stream>>>(node_h, W3, nodeT, nodePre, nullptr, nullptr, N, NH, EH, 0);
        // agg = segment_sum(relu(nodeT[src] + W2e), dst)
        agg_kernel<<<N / 4, dim3(32, 4), 0, stream>>>(nodeT, W2e, rp, eid, srcp, aggp);
        // node_h = relu(U1x + agg @ U2)
        gemm_kernel<<<dim3(NH / 64, N / 64), 256, 0, stream>>>(aggp, U2, node_h, U1x, nullptr, nullptr, N, EH, NH, 1);
    }

    // ---- pick-atom MLP ----
    // molPart[b] = mol_a[b] @ M1w[128:384,:] + M1b   (per-molecule, 32x fewer rows)
    gemm_kernel<<<dim3(256 / 64, B / 64), 256, 0, stream>>>(mol_a, M1w + 128 * 256, molPart, nullptr, nullptr, M1b, B, MA, 256, 0);
    // x1 = relu(node_h @ M1w[0:128,:] + molPart[batch])
    gemm_kernel<<<dim3(256 / 64, N / 64), 256, 0, stream>>>(node_h, M1w, x1, molPart, batch, nullptr, N, NH, 256, 1);
    // x2 = relu(x1 @ M2w + M2b)
    gemm_kernel<<<dim3(128 / 64, N / 64), 256, 0, stream>>>(x1, M2w, x2, nullptr, nullptr, M2b, N, 256, 128, 1);
    // x3 = relu(x2 @ M3w + M3b)
    gemm_kernel<<<dim3(64 / 64, N / 64), 256, 0, stream>>>(x2, M3w, x3, nullptr, nullptr, M3b, N, 128, 64, 1);
    // out = (x3 @ M4w + M4b >= 0)  [sigmoid(z)>=0.5 <=> z>=0]  (int32 output)
    final_kernel<<<ceil_div(N * 64, 256), 256, 0, stream>>>(x3, M4w, M4b, (int*)d_out, N);
}

// Round 3
// 1386.635 us; speedup vs baseline: 1.0420x; 1.0420x over previous
//
#include <hip/hip_runtime.h>
#include <cstddef>

#define NF 64
#define EF 16
#define NH 128
#define EH 128
#define MA 256

static inline int ceil_div(int a, int b) { return (a + b - 1) / b; }

// ---------------- fp32 GEMM, 128x128 tile, 8x8 microtile ----------------
// C[M,Nc] = act( A[gatherA? gatherA[r] : r][K] @ Bw[K,Nc] + addR[addIdx? addIdx[r]:r] + bias )
// 256 threads. M%128==0, Nc(col-block)%128==0, K%16==0.
__global__ __launch_bounds__(256) void gemm128_kernel(
    const float* __restrict__ A, const float* __restrict__ Bw,
    float* __restrict__ C,
    const float* __restrict__ addR, const int* __restrict__ addIdx,
    const float* __restrict__ bias, const int* __restrict__ gatherA,
    int M, int K, int Nc, int doRelu)
{
    __shared__ float As[16][132];   // [k][m], pad
    __shared__ float Bs[16][132];   // [k][n], pad
    const int tid = threadIdx.x;
    const int tx = tid & 15;        // n: 8 cols each
    const int ty = tid >> 4;        // m: 8 rows each
    const int m0 = blockIdx.y << 7;
    const int n0 = blockIdx.x << 7;

    // staging roles
    const int lr = tid >> 1;              // A row 0..127
    const int lc = (tid & 1) << 3;        // A col 0 or 8
    const int br = tid >> 4;              // B k-row 0..15
    const int bc = (tid & 15) << 3;       // B col 0..120

    float acc[8][8];
#pragma unroll
    for (int i = 0; i < 8; ++i)
#pragma unroll
        for (int j = 0; j < 8; ++j) acc[i][j] = 0.0f;

    int arow = gatherA ? gatherA[m0 + lr] : (m0 + lr);
    const float* aptr = A + (size_t)arow * K + lc;

    for (int k0 = 0; k0 < K; k0 += 16) {
        float4 a0 = *(const float4*)(aptr + k0);
        float4 a1 = *(const float4*)(aptr + k0 + 4);
        float4 b0 = *(const float4*)(Bw + (size_t)(k0 + br) * Nc + n0 + bc);
        float4 b1 = *(const float4*)(Bw + (size_t)(k0 + br) * Nc + n0 + bc + 4);
        __syncthreads();
        As[lc + 0][lr] = a0.x; As[lc + 1][lr] = a0.y; As[lc + 2][lr] = a0.z; As[lc + 3][lr] = a0.w;
        As[lc + 4][lr] = a1.x; As[lc + 5][lr] = a1.y; As[lc + 6][lr] = a1.z; As[lc + 7][lr] = a1.w;
        *(float4*)&Bs[br][bc] = b0;
        *(float4*)&Bs[br][bc + 4] = b1;
        __syncthreads();
#pragma unroll
        for (int kk = 0; kk < 16; ++kk) {
            float4 av0 = *(const float4*)&As[kk][ty * 8];
            float4 av1 = *(const float4*)&As[kk][ty * 8 + 4];
            float4 bv0 = *(const float4*)&Bs[kk][tx * 8];
            float4 bv1 = *(const float4*)&Bs[kk][tx * 8 + 4];
            float a[8] = {av0.x, av0.y, av0.z, av0.w, av1.x, av1.y, av1.z, av1.w};
            float b[8] = {bv0.x, bv0.y, bv0.z, bv0.w, bv1.x, bv1.y, bv1.z, bv1.w};
#pragma unroll
            for (int i = 0; i < 8; ++i)
#pragma unroll
                for (int j = 0; j < 8; ++j)
                    acc[i][j] = fmaf(a[i], b[j], acc[i][j]);
        }
    }

    const int c = n0 + tx * 8;
    float4 bvl = make_float4(0.f, 0.f, 0.f, 0.f), bvh = bvl;
    if (bias) { bvl = *(const float4*)(bias + c); bvh = *(const float4*)(bias + c + 4); }
#pragma unroll
    for (int i = 0; i < 8; ++i) {
        int r = m0 + ty * 8 + i;
        float4 vl = make_float4(acc[i][0], acc[i][1], acc[i][2], acc[i][3]);
        float4 vh = make_float4(acc[i][4], acc[i][5], acc[i][6], acc[i][7]);
        if (addR) {
            int ar = addIdx ? addIdx[r] : r;
            float4 al = *(const float4*)(addR + (size_t)ar * Nc + c);
            float4 ah = *(const float4*)(addR + (size_t)ar * Nc + c + 4);
            vl.x += al.x; vl.y += al.y; vl.z += al.z; vl.w += al.w;
            vh.x += ah.x; vh.y += ah.y; vh.z += ah.z; vh.w += ah.w;
        }
        vl.x += bvl.x; vl.y += bvl.y; vl.z += bvl.z; vl.w += bvl.w;
        vh.x += bvh.x; vh.y += bvh.y; vh.z += bvh.z; vh.w += bvh.w;
        if (doRelu) {
            vl.x = fmaxf(vl.x, 0.f); vl.y = fmaxf(vl.y, 0.f); vl.z = fmaxf(vl.z, 0.f); vl.w = fmaxf(vl.w, 0.f);
            vh.x = fmaxf(vh.x, 0.f); vh.y = fmaxf(vh.y, 0.f); vh.z = fmaxf(vh.z, 0.f); vh.w = fmaxf(vh.w, 0.f);
        }
        *(float4*)(C + (size_t)r * Nc + c) = vl;
        *(float4*)(C + (size_t)r * Nc + c + 4) = vh;
    }
}

// ---------------- fp32 GEMM, 64x64 tile (small shapes) ----------------
__global__ __launch_bounds__(256) void gemm_kernel(
    const float* __restrict__ A, const float* __restrict__ Bw,
    float* __restrict__ C,
    const float* __restrict__ addR, const int* __restrict__ addIdx,
    const float* __restrict__ bias,
    int M, int K, int Nc, int doRelu)
{
    __shared__ float As[16][64];
    __shared__ float Bs[16][64];
    const int tid = threadIdx.x;
    const int tx = tid & 15, ty = tid >> 4;
    const int m0 = blockIdx.y << 6;
    const int n0 = blockIdx.x << 6;
    const int lr = tid >> 2;
    const int lc = (tid & 3) << 2;
    const int bkr = tid >> 4;
    const int bc = (tid & 15) << 2;

    float acc[4][4];
#pragma unroll
    for (int i = 0; i < 4; ++i)
#pragma unroll
        for (int j = 0; j < 4; ++j) acc[i][j] = 0.0f;

    for (int k0 = 0; k0 < K; k0 += 16) {
        float4 a4 = *(const float4*)(A + (size_t)(m0 + lr) * K + (k0 + lc));
        float4 b4 = *(const float4*)(Bw + (size_t)(k0 + bkr) * Nc + (n0 + bc));
        __syncthreads();
        As[lc + 0][lr] = a4.x;
        As[lc + 1][lr] = a4.y;
        As[lc + 2][lr] = a4.z;
        As[lc + 3][lr] = a4.w;
        *(float4*)&Bs[bkr][bc] = b4;
        __syncthreads();
#pragma unroll
        for (int kk = 0; kk < 16; ++kk) {
            float a0 = As[kk][ty * 4 + 0];
            float a1 = As[kk][ty * 4 + 1];
            float a2 = As[kk][ty * 4 + 2];
            float a3 = As[kk][ty * 4 + 3];
            float b0 = Bs[kk][tx * 4 + 0];
            float b1 = Bs[kk][tx * 4 + 1];
            float b2 = Bs[kk][tx * 4 + 2];
            float b3 = Bs[kk][tx * 4 + 3];
            acc[0][0] += a0 * b0; acc[0][1] += a0 * b1; acc[0][2] += a0 * b2; acc[0][3] += a0 * b3;
            acc[1][0] += a1 * b0; acc[1][1] += a1 * b1; acc[1][2] += a1 * b2; acc[1][3] += a1 * b3;
            acc[2][0] += a2 * b0; acc[2][1] += a2 * b1; acc[2][2] += a2 * b2; acc[2][3] += a2 * b3;
            acc[3][0] += a3 * b0; acc[3][1] += a3 * b1; acc[3][2] += a3 * b2; acc[3][3] += a3 * b3;
        }
    }

    const int c = n0 + tx * 4;
    float4 bv = make_float4(0.f, 0.f, 0.f, 0.f);
    if (bias) bv = *(const float4*)(bias + c);
#pragma unroll
    for (int i = 0; i < 4; ++i) {
        int r = m0 + ty * 4 + i;
        float4 v = make_float4(acc[i][0], acc[i][1], acc[i][2], acc[i][3]);
        if (addR) {
            int ar = addIdx ? addIdx[r] : r;
            float4 ad = *(const float4*)(addR + (size_t)ar * Nc + c);
            v.x += ad.x; v.y += ad.y; v.z += ad.z; v.w += ad.w;
        }
        v.x += bv.x; v.y += bv.y; v.z += bv.z; v.w += bv.w;
        if (doRelu) {
            v.x = fmaxf(v.x, 0.f); v.y = fmaxf(v.y, 0.f);
            v.z = fmaxf(v.z, 0.f); v.w = fmaxf(v.w, 0.f);
        }
        *(float4*)(C + (size_t)r * Nc + c) = v;
    }
}

// ---------------- CSR build ----------------
__global__ __launch_bounds__(256) void hist_kernel(const int* __restrict__ dst, int* __restrict__ deg, int E) {
    int e = blockIdx.x * 256 + threadIdx.x;
    if (e < E) atomicAdd(&deg[dst[e]], 1);
}

__global__ __launch_bounds__(256) void scan_block_kernel(const int* __restrict__ deg, int* __restrict__ rp,
                                                         int* __restrict__ bsum) {
    __shared__ int buf[256];
    int tid = threadIdx.x;
    int i = blockIdx.x * 256 + tid;
    int v = deg[i];
    buf[tid] = v;
    __syncthreads();
    for (int off = 1; off < 256; off <<= 1) {
        int t = (tid >= off) ? buf[tid - off] : 0;
        __syncthreads();
        buf[tid] += t;
        __syncthreads();
    }
    rp[i] = buf[tid] - v;
    if (tid == 255) bsum[blockIdx.x] = buf[255];
}

__global__ __launch_bounds__(256) void scan_top_kernel(const int* __restrict__ bsum, int* __restrict__ boff,
                                                       int* __restrict__ rp, int N) {
    __shared__ int buf[256];
    int tid = threadIdx.x;
    int v = bsum[tid];
    buf[tid] = v;
    __syncthreads();
    for (int off = 1; off < 256; off <<= 1) {
        int t = (tid >= off) ? buf[tid - off] : 0;
        __syncthreads();
        buf[tid] += t;
        __syncthreads();
    }
    boff[tid] = buf[tid] - v;
    if (tid == 255) rp[N] = buf[255];
}

__global__ __launch_bounds__(256) void scan_add_kernel(int* __restrict__ rp, int* __restrict__ cursor,
                                                       const int* __restrict__ boff) {
    int tid = threadIdx.x;
    int i = blockIdx.x * 256 + tid;
    int v = rp[i] + boff[blockIdx.x];
    rp[i] = v;
    cursor[i] = v;
}

// also emits srcS[p] = src[eid[p]] so agg reads sequentially
__global__ __launch_bounds__(256) void scatter_kernel(const int* __restrict__ dst, const int* __restrict__ src,
                                                      int* __restrict__ cursor,
                                                      int* __restrict__ eid, int* __restrict__ srcS, int E) {
    int e = blockIdx.x * 256 + threadIdx.x;
    if (e < E) {
        int p = atomicAdd(&cursor[dst[e]], 1);
        eid[p] = e;
        srcS[p] = src[e];
    }
}

// ---------------- elementwise relu copy ----------------
__global__ __launch_bounds__(256) void relu_copy_kernel(const float* __restrict__ in, float* __restrict__ out, int n4) {
    int i = blockIdx.x * 256 + threadIdx.x;
    if (i < n4) {
        float4 v = ((const float4*)in)[i];
        v.x = fmaxf(v.x, 0.f); v.y = fmaxf(v.y, 0.f);
        v.z = fmaxf(v.z, 0.f); v.w = fmaxf(v.w, 0.f);
        ((float4*)out)[i] = v;
    }
}

// ---------------- edge aggregation via CSR (gather, sequential srcS/W2eS) ----------------
// agg[n][c] = sum_{p in [rp[n],rp[n+1])} relu(nodeT[srcS[p]][c] + W2eS[p][c])
__global__ __launch_bounds__(128) void agg_kernel(const float* __restrict__ nodeT, const float* __restrict__ W2eS,
                                                  const int* __restrict__ rp, const int* __restrict__ srcS,
                                                  float* __restrict__ agg) {
    int n = blockIdx.x * 4 + threadIdx.y;
    int c = threadIdx.x << 2;
    int p0 = rp[n], p1 = rp[n + 1];
    float4 s = make_float4(0.f, 0.f, 0.f, 0.f);
    for (int p = p0; p < p1; ++p) {
        int sn = srcS[p];
        float4 t = *(const float4*)(nodeT + (size_t)sn * EH + c);
        float4 w = *(const float4*)(W2eS + (size_t)p * EH + c);
        s.x += fmaxf(t.x + w.x, 0.f);
        s.y += fmaxf(t.y + w.y, 0.f);
        s.z += fmaxf(t.z + w.z, 0.f);
        s.w += fmaxf(t.w + w.w, 0.f);
    }
    *(float4*)(agg + (size_t)n * EH + c) = s;
}

// ---------------- final layer: z = x3 @ M4w + b; out = (z>=0) as int32 ----------------
__global__ __launch_bounds__(256) void final_kernel(const float* __restrict__ x3, const float* __restrict__ w,
                                                    const float* __restrict__ b, int* __restrict__ out, int Nn) {
    int g = blockIdx.x * 256 + threadIdx.x;
    int n = g >> 6;
    int lane = threadIdx.x & 63;
    if (n < Nn) {
        float v = x3[(size_t)n * 64 + lane] * w[lane];
#pragma unroll
        for (int off = 32; off > 0; off >>= 1) v += __shfl_xor(v, off, 64);
        if (lane == 0) out[n] = (v + b[0]) >= 0.f ? 1 : 0;
    }
}

extern "C" void kernel_launch(void* const* d_in, const int* in_sizes, int n_in,
                              void* d_out, int out_size, void* d_ws, size_t ws_size,
                              hipStream_t stream)
{
    const float* mol_a = (const float*)d_in[0];
    const float* nf    = (const float*)d_in[1];
    const float* ef    = (const float*)d_in[2];
    const int*   edges = (const int*)d_in[5];
    const int*   batch = (const int*)d_in[6];
    const float* W1  = (const float*)d_in[7];
    const float* W2  = (const float*)d_in[8];
    const float* W3  = (const float*)d_in[9];
    const float* U1  = (const float*)d_in[10];
    const float* U2  = (const float*)d_in[11];
    const float* M1w = (const float*)d_in[12];
    const float* M1b = (const float*)d_in[13];
    const float* M2w = (const float*)d_in[14];
    const float* M2b = (const float*)d_in[15];
    const float* M3w = (const float*)d_in[16];
    const float* M3b = (const float*)d_in[17];
    const float* M4w = (const float*)d_in[18];
    const float* M4b = (const float*)d_in[19];

    const int N = in_sizes[3] / NH;   // 65536
    const int E = in_sizes[4] / EH;   // 262144
    const int B = in_sizes[0] / MA;   // 2048
    const int* srcp = edges;
    const int* dstp = edges + E;

    char* ws = (char*)d_ws;
    size_t off = 0;
    auto alloc = [&](size_t bytes) -> char* {
        char* p = ws + off;
        off = (off + bytes + 255) & ~(size_t)255;
        return p;
    };
    int* deg     = (int*)alloc((size_t)N * 4);
    int* rp      = (int*)alloc(((size_t)N + 1) * 4);
    int* cursor  = (int*)alloc((size_t)N * 4);
    int* bsum    = (int*)alloc(256 * 4);
    int* boff    = (int*)alloc(256 * 4);
    int* eid     = (int*)alloc((size_t)E * 4);
    int* srcS    = (int*)alloc((size_t)E * 4);
    float* nodePre = (float*)alloc((size_t)N * EH * 4);
    float* U1x     = (float*)alloc((size_t)N * NH * 4);
    float* node_h  = (float*)alloc((size_t)N * NH * 4);
    float* nodeT   = (float*)alloc((size_t)N * EH * 4);
    float* aggp    = (float*)alloc((size_t)N * EH * 4);
    float* molPart = (float*)alloc((size_t)B * 256 * 4);
    float* W2eS    = (float*)alloc((size_t)E * EH * 4);
    // MLP phase reuses dead buffers:
    float* x1 = (float*)W2eS;  // [N,256] (67MB <= 134MB)
    float* x2 = nodeT;         // [N,128]
    float* x3 = aggp;          // [N,64]

    // ---- CSR build (dst is loop-invariant) ----
    hipMemsetAsync(deg, 0, (size_t)N * 4, stream);
    hist_kernel<<<ceil_div(E, 256), 256, 0, stream>>>(dstp, deg, E);
    scan_block_kernel<<<N / 256, 256, 0, stream>>>(deg, rp, bsum);
    scan_top_kernel<<<1, 256, 0, stream>>>(bsum, boff, rp, N);
    scan_add_kernel<<<N / 256, 256, 0, stream>>>(rp, cursor, boff);
    scatter_kernel<<<ceil_div(E, 256), 256, 0, stream>>>(dstp, srcp, cursor, eid, srcS, E);

    // ---- loop-invariant precompute ----
    gemm128_kernel<<<dim3(1, N / 128), 256, 0, stream>>>(nf, W1, nodePre, nullptr, nullptr, nullptr, nullptr, N, NF, EH, 0);
    // W2eS[p] = ef[eid[p]] @ W2  (CSR-ordered, so agg reads it sequentially)
    gemm128_kernel<<<dim3(1, E / 128), 256, 0, stream>>>(ef, W2, W2eS, nullptr, nullptr, nullptr, eid, E, EF, EH, 0);
    gemm128_kernel<<<dim3(1, N / 128), 256, 0, stream>>>(nf, U1, U1x, nullptr, nullptr, nullptr, nullptr, N, NF, NH, 0);

    // ---- step 1: edge_h0 == 0 -> agg == 0 -> node_h = relu(U1x) ----
    relu_copy_kernel<<<(N * NH / 4) / 256, 256, 0, stream>>>(U1x, node_h, N * NH / 4);

    // ---- steps 2..8 ----
    for (int s = 0; s < 7; ++s) {
        gemm128_kernel<<<dim3(1, N / 128), 256, 0, stream>>>(node_h, W3, nodeT, nodePre, nullptr, nullptr, nullptr, N, NH, EH, 0);
        agg_kernel<<<N / 4, dim3(32, 4), 0, stream>>>(nodeT, W2eS, rp, srcS, aggp);
        gemm128_kernel<<<dim3(1, N / 128), 256, 0, stream>>>(aggp, U2, node_h, U1x, nullptr, nullptr, nullptr, N, EH, NH, 1);
    }

    // ---- pick-atom MLP ----
    gemm_kernel<<<dim3(256 / 64, B / 64), 256, 0, stream>>>(mol_a, M1w + 128 * 256, molPart, nullptr, nullptr, M1b, B, MA, 256, 0);
    gemm128_kernel<<<dim3(2, N / 128), 256, 0, stream>>>(node_h, M1w, x1, molPart, batch, nullptr, nullptr, N, NH, 256, 1);
    gemm128_kernel<<<dim3(1, N / 128), 256, 0, stream>>>(x1, M2w, x2, nullptr, nullptr, M2b, nullptr, N, 256, 128, 1);
    gemm_kernel<<<dim3(1, N / 64), 256, 0, stream>>>(x2, M3w, x3, nullptr, nullptr, M3b, N, 128, 64, 1);
    final_kernel<<<ceil_div(N * 64, 256), 256, 0, stream>>>(x3, M4w, M4b, (int*)d_out, N);
}